// Round 1
// baseline (1489.804 us; speedup 1.0000x reference)
//
#include <hip/hip_runtime.h>
#include <cstdint>
#include <cstddef>

// ---------------------------------------------------------------- types
typedef __bf16 bf16_t;
typedef __bf16 bf16x8 __attribute__((ext_vector_type(8)));
typedef __bf16 bf16x4 __attribute__((ext_vector_type(4)));
typedef float  f32x4  __attribute__((ext_vector_type(4)));

#define DEV __device__ __forceinline__

static constexpr int   BATCH = 2;
static constexpr int   NTOK  = 1024;
static constexpr int   DIM   = 1024;
static constexpr int   HEADS = 16;
static constexpr int   DHEAD = 64;
static constexpr int   INNER = 1024;
static constexpr int   FF    = 4096;
static constexpr int   MROWS = BATCH * NTOK;      // 2048 token rows
static constexpr float SCALE = 0.125f;            // 64^-0.5

// ------------------------------------------------------- global->LDS DMA
DEV void load_lds16(const bf16_t* g, bf16_t* s) {
  __builtin_amdgcn_global_load_lds(
      (const __attribute__((address_space(1))) void*)g,
      (__attribute__((address_space(3))) void*)s, 16, 0, 0);
}

// ------------------------------------------------------------ reductions
DEV float wave_sum(float v) {
#pragma unroll
  for (int m = 1; m < 64; m <<= 1) v += __shfl_xor(v, m, 64);
  return v;
}
DEV float wave_max(float v) {
#pragma unroll
  for (int m = 1; m < 64; m <<= 1) v = fmaxf(v, __shfl_xor(v, m, 64));
  return v;
}
DEV float block_sum(float v, float* sb) {
  v = wave_sum(v);
  __syncthreads();
  if ((threadIdx.x & 63) == 0) sb[threadIdx.x >> 6] = v;
  __syncthreads();
  return sb[0] + sb[1] + sb[2] + sb[3];
}
DEV float block_max(float v, float* sb) {
  v = wave_max(v);
  __syncthreads();
  if ((threadIdx.x & 63) == 0) sb[threadIdx.x >> 6] = v;
  __syncthreads();
  return fmaxf(fmaxf(sb[0], sb[1]), fmaxf(sb[2], sb[3]));
}

// ------------------------------------------------------------------ GEMM
// C[M,N] = A[M,K] @ B[K,N], with B given transposed: BT[N][K] (row-major).
// A, BT bf16. Fragment layout (verified m89/m91/m120):
//   A frag:  A[m = lane&15][k = (lane>>4)*8 + j]   -> 8 contiguous bf16
//   B frag:  BT[n = lane&15][k = (lane>>4)*8 + j]  -> 8 contiguous bf16
//   C/D:     col = lane&15, row = (lane>>4)*4 + reg
// Batch via blockIdx.z with two-level strides: off = (z>>4)*s0 + (z&15)*s1.
// MODE 0: C(bf16) = alpha * acc
// MODE 1: C(bf16) = acc + bias[col]
// MODE 2: C(f32) += (acc + bias[col]) * ls[col]   (residual update in place)
template <int BM, int BN, int WR, int WC, int MODE>
__global__ __launch_bounds__(256) void gemm_bt(
    const bf16_t* __restrict__ A, long sA0, long sA1, int lda,
    const bf16_t* __restrict__ B, long sB0, long sB1, int ldb,
    void* __restrict__ Cv, long sC0, long sC1, int ldc,
    int K, float alpha, const float* __restrict__ bias,
    const float* __restrict__ ls) {
  constexpr int TM = BM / WR / 16;
  constexpr int TN = BN / WC / 16;
  __shared__ __attribute__((aligned(16))) bf16_t As[BM * 32];
  __shared__ __attribute__((aligned(16))) bf16_t Bs[BN * 32];

  const int tid  = threadIdx.x;
  const int lane = tid & 63, wave = tid >> 6;
  const int z  = blockIdx.z;
  const int zh = z >> 4, zl = z & 15;
  A += (size_t)zh * sA0 + (size_t)zl * sA1;
  B += (size_t)zh * sB0 + (size_t)zl * sB1;

  const int m0 = blockIdx.y * BM, n0 = blockIdx.x * BN;
  const int wm = (wave / WC) * (BM / WR);
  const int wn = (wave % WC) * (BN / WC);
  const int fm = lane & 15, quad = lane >> 4;

  f32x4 acc[TM][TN] = {};

  for (int k0 = 0; k0 < K; k0 += 32) {
#pragma unroll
    for (int c = tid; c < BM * 4; c += 256) {
      const int row = c >> 2, kc = (c & 3) << 3;
      load_lds16(A + (size_t)(m0 + row) * lda + k0 + kc, &As[c * 8]);
    }
#pragma unroll
    for (int c = tid; c < BN * 4; c += 256) {
      const int row = c >> 2, kc = (c & 3) << 3;
      load_lds16(B + (size_t)(n0 + row) * ldb + k0 + kc, &Bs[c * 8]);
    }
    __syncthreads();

    bf16x8 af[TM], bfr[TN];
#pragma unroll
    for (int i = 0; i < TM; ++i)
      af[i] = *(const bf16x8*)&As[(wm + i * 16 + fm) * 32 + quad * 8];
#pragma unroll
    for (int j = 0; j < TN; ++j)
      bfr[j] = *(const bf16x8*)&Bs[(wn + j * 16 + fm) * 32 + quad * 8];
#pragma unroll
    for (int i = 0; i < TM; ++i)
#pragma unroll
      for (int j = 0; j < TN; ++j)
        acc[i][j] = __builtin_amdgcn_mfma_f32_16x16x32_bf16(af[i], bfr[j],
                                                            acc[i][j], 0, 0, 0);
    __syncthreads();
  }

  const size_t coff = (size_t)zh * sC0 + (size_t)zl * sC1;
#pragma unroll
  for (int i = 0; i < TM; ++i) {
#pragma unroll
    for (int j = 0; j < TN; ++j) {
      const int col  = n0 + wn + j * 16 + fm;
      const int rowb = m0 + wm + i * 16 + quad * 4;
#pragma unroll
      for (int r = 0; r < 4; ++r) {
        const float  v   = acc[i][j][r];
        const size_t idx = coff + (size_t)(rowb + r) * ldc + col;
        if constexpr (MODE == 0) {
          ((bf16_t*)Cv)[idx] = (bf16_t)(v * alpha);
        } else if constexpr (MODE == 1) {
          ((bf16_t*)Cv)[idx] = (bf16_t)(v + bias[col]);
        } else {
          float* C = (float*)Cv;
          C[idx]   = C[idx] + (v + bias[col]) * ls[col];
        }
      }
    }
  }
}

// ------------------------------------------------- weight transpose+cast
// W[K][N] fp32 -> WT[N][K] bf16.  grid(N/32, K/32), 256 thr.
__global__ __launch_bounds__(256) void transpose_w(const float* __restrict__ W,
                                                   bf16_t* __restrict__ WT,
                                                   int K, int N) {
  __shared__ float t[32][33];
  const int n0 = blockIdx.x * 32, k0 = blockIdx.y * 32;
  const int tx = threadIdx.x & 31, ty = threadIdx.x >> 5;
#pragma unroll
  for (int s = 0; s < 4; ++s)
    t[ty + 8 * s][tx] = W[(size_t)(k0 + ty + 8 * s) * N + n0 + tx];
  __syncthreads();
#pragma unroll
  for (int s = 0; s < 4; ++s)
    WT[(size_t)(n0 + ty + 8 * s) * K + k0 + tx] = (bf16_t)t[tx][ty + 8 * s];
}

// ----------------------------------------------------- V transpose (bf16)
// qkv[b*1024+tok][2048 + h*64 + d] -> vT[z=b*16+h][d][tok]
__global__ __launch_bounds__(256) void transpose_v(const bf16_t* __restrict__ qkv,
                                                   bf16_t* __restrict__ vT) {
  __shared__ bf16_t t[32][33];
  const int z = blockIdx.z, b = z >> 4, h = z & 15;
  const int d0 = blockIdx.y * 32, n0 = blockIdx.x * 32;
  const int tx = threadIdx.x & 31, ty = threadIdx.x >> 5;
  const bf16_t* src = qkv + (size_t)b * NTOK * 3072 + 2048 + h * 64;
#pragma unroll
  for (int s = 0; s < 4; ++s)
    t[ty + 8 * s][tx] = src[(size_t)(n0 + ty + 8 * s) * 3072 + d0 + tx];
  __syncthreads();
  bf16_t* dst = vT + (size_t)z * DHEAD * NTOK;
#pragma unroll
  for (int s = 0; s < 4; ++s)
    dst[(size_t)(d0 + ty + 8 * s) * NTOK + n0 + tx] = t[tx][ty + 8 * s];
}

// -------------------------------------------------------------- layernorm
// one block per row of 1024; writes bf16.
__global__ __launch_bounds__(256) void ln_kernel(const float* __restrict__ x,
                                                 const float* __restrict__ w,
                                                 const float* __restrict__ b,
                                                 bf16_t* __restrict__ out) {
  __shared__ float sb[4];
  const int row = blockIdx.x, tid = threadIdx.x;
  const float4 v = ((const float4*)(x + (size_t)row * DIM))[tid];
  float s = v.x + v.y + v.z + v.w;
  s = block_sum(s, sb);
  const float mu = s * (1.f / DIM);
  const float dx = v.x - mu, dy = v.y - mu, dz = v.z - mu, dw = v.w - mu;
  float q = dx * dx + dy * dy + dz * dz + dw * dw;
  q = block_sum(q, sb);
  const float rstd = rsqrtf(q * (1.f / DIM) + 1e-5f);
  const float4 wv = ((const float4*)w)[tid];
  const float4 bv = ((const float4*)b)[tid];
  bf16x4 o;
  o[0] = (bf16_t)(dx * rstd * wv.x + bv.x);
  o[1] = (bf16_t)(dy * rstd * wv.y + bv.y);
  o[2] = (bf16_t)(dz * rstd * wv.z + bv.z);
  o[3] = (bf16_t)(dw * rstd * wv.w + bv.w);
  ((bf16x4*)(out + (size_t)row * DIM))[tid] = o;
}

// ---------------------------------------------------------------- softmax
// in-place row softmax over 1024 bf16 entries (scores already *SCALE).
__global__ __launch_bounds__(256) void softmax_kernel(bf16_t* __restrict__ S) {
  __shared__ float sb[4];
  const size_t row = blockIdx.x;
  const int    tid = threadIdx.x;
  bf16x4 v = ((bf16x4*)(S + row * 1024))[tid];
  float f0 = v[0], f1 = v[1], f2 = v[2], f3 = v[3];
  float m = fmaxf(fmaxf(f0, f1), fmaxf(f2, f3));
  m = block_max(m, sb);
  const float e0 = __expf(f0 - m), e1 = __expf(f1 - m);
  const float e2 = __expf(f2 - m), e3 = __expf(f3 - m);
  float s = e0 + e1 + e2 + e3;
  s = block_sum(s, sb);
  const float inv = 1.f / s;
  v[0] = (bf16_t)(e0 * inv);
  v[1] = (bf16_t)(e1 * inv);
  v[2] = (bf16_t)(e2 * inv);
  v[3] = (bf16_t)(e3 * inv);
  ((bf16x4*)(S + row * 1024))[tid] = v;
}

// ------------------------------------------------------------------ geglu
// u[2048][8192] -> ff[2048][4096]:  ff = a * gelu_exact(g)
__global__ __launch_bounds__(256) void geglu_kernel(const bf16_t* __restrict__ u,
                                                    bf16_t* __restrict__ ff) {
  const int g   = blockIdx.x * 256 + threadIdx.x;  // group of 4 elements
  const int row = g >> 10, cg = (g & 1023) * 4;
  const bf16x4 av = *(const bf16x4*)(u + (size_t)row * 8192 + cg);
  const bf16x4 gv = *(const bf16x4*)(u + (size_t)row * 8192 + 4096 + cg);
  bf16x4 o;
#pragma unroll
  for (int c = 0; c < 4; ++c) {
    const float gx = (float)gv[c];
    const float ge = 0.5f * gx * (1.f + erff(gx * 0.70710678118654752f));
    o[c] = (bf16_t)((float)av[c] * ge);
  }
  *(bf16x4*)(ff + (size_t)row * 4096 + cg) = o;
}

// ------------------------------------------------------------------ launch
extern "C" void kernel_launch(void* const* d_in, const int* in_sizes, int n_in,
                              void* d_out, int out_size, void* d_ws,
                              size_t ws_size, hipStream_t stream) {
  const float* x_in = (const float*)d_in[0];
  const float* ln1w = (const float*)d_in[1];
  const float* ln1b = (const float*)d_in[2];
  const float* wqkv = (const float*)d_in[3];
  const float* wout = (const float*)d_in[4];
  const float* bout = (const float*)d_in[5];
  const float* ls1  = (const float*)d_in[6];
  const float* ln2w = (const float*)d_in[7];
  const float* ln2b = (const float*)d_in[8];
  const float* wff1 = (const float*)d_in[9];
  const float* bff1 = (const float*)d_in[10];
  const float* wff2 = (const float*)d_in[11];
  const float* bff2 = (const float*)d_in[12];
  const float* ls2  = (const float*)d_in[13];
  float*       xout = (float*)d_out;

  // -------- workspace carve-up (~120 MB)
  char*   ws     = (char*)d_ws;
  bf16_t* wqkvT  = (bf16_t*)ws; ws += (size_t)3072 * 1024 * 2;   // 6.3 MB
  bf16_t* woutT  = (bf16_t*)ws; ws += (size_t)1024 * 1024 * 2;   // 2.1 MB
  bf16_t* wff1T  = (bf16_t*)ws; ws += (size_t)8192 * 1024 * 2;   // 16.8 MB
  bf16_t* wff2T  = (bf16_t*)ws; ws += (size_t)1024 * 4096 * 2;   // 8.4 MB
  bf16_t* h_bf   = (bf16_t*)ws; ws += (size_t)MROWS * 1024 * 2;  // 4.2 MB
  bf16_t* qkv_bf = (bf16_t*)ws; ws += (size_t)MROWS * 3072 * 2;  // 12.6 MB
  bf16_t* o_bf   = (bf16_t*)ws; ws += (size_t)MROWS * 1024 * 2;  // 4.2 MB
  bf16_t* vT     = (bf16_t*)ws; ws += (size_t)32 * 64 * 1024 * 2;// 4.2 MB
  // scores region reused by FF activations (disjoint phases)
  bf16_t* Sb     = (bf16_t*)ws;                   // 32*1024*1024*2 = 67.1 MB
  bf16_t* u_bf   = (bf16_t*)ws;                   // 2048*8192*2   = 33.6 MB
  bf16_t* ff_bf  = (bf16_t*)(ws + 33554432);      // 2048*4096*2   = 16.8 MB
  if (ws_size < (size_t)(ws - (char*)d_ws) + 67108864) return;  // visible fail

  // running x lives in d_out
  hipMemcpyAsync(xout, x_in, (size_t)MROWS * DIM * 4,
                 hipMemcpyDeviceToDevice, stream);

  for (int l = 0; l < 4; ++l) {
    // ---- per-layer weight transpose+cast
    transpose_w<<<dim3(3072 / 32, 1024 / 32), 256, 0, stream>>>(
        wqkv + (size_t)l * 1024 * 3072, wqkvT, 1024, 3072);
    transpose_w<<<dim3(1024 / 32, 1024 / 32), 256, 0, stream>>>(
        wout + (size_t)l * 1024 * 1024, woutT, 1024, 1024);
    transpose_w<<<dim3(8192 / 32, 1024 / 32), 256, 0, stream>>>(
        wff1 + (size_t)l * 1024 * 8192, wff1T, 1024, 8192);
    transpose_w<<<dim3(1024 / 32, 4096 / 32), 256, 0, stream>>>(
        wff2 + (size_t)l * 4096 * 1024, wff2T, 4096, 1024);

    // ---- attention
    ln_kernel<<<MROWS, 256, 0, stream>>>(xout, ln1w + l * 1024,
                                         ln1b + l * 1024, h_bf);
    gemm_bt<128, 128, 2, 2, 0><<<dim3(24, 16, 1), 256, 0, stream>>>(
        h_bf, 0, 0, 1024, wqkvT, 0, 0, 1024, qkv_bf, 0, 0, 3072, 1024, 1.f,
        nullptr, nullptr);
    // S = SCALE * q @ k^T  per (b,h)
    gemm_bt<128, 128, 2, 2, 0><<<dim3(8, 8, 32), 256, 0, stream>>>(
        qkv_bf, (long)1024 * 3072, 64, 3072,
        qkv_bf + 1024, (long)1024 * 3072, 64, 3072,
        Sb, (long)16 * 1024 * 1024, (long)1024 * 1024, 1024,
        64, SCALE, nullptr, nullptr);
    softmax_kernel<<<32 * 1024, 256, 0, stream>>>(Sb);
    transpose_v<<<dim3(32, 2, 32), 256, 0, stream>>>(qkv_bf, vT);
    // O = P @ V  per (b,h);  C written head-major into o_bf[token][h*64+d]
    gemm_bt<128, 64, 4, 1, 0><<<dim3(1, 8, 32), 256, 0, stream>>>(
        Sb, (long)16 * 1024 * 1024, (long)1024 * 1024, 1024,
        vT, (long)16 * 64 * 1024, (long)64 * 1024, 1024,
        o_bf, (long)1024 * 1024, 64, 1024,
        1024, 1.f, nullptr, nullptr);
    // x += (o @ w_out + b_out) * ls1
    gemm_bt<128, 128, 2, 2, 2><<<dim3(8, 16, 1), 256, 0, stream>>>(
        o_bf, 0, 0, 1024, woutT, 0, 0, 1024, xout, 0, 0, 1024, 1024, 1.f,
        bout + l * 1024, ls1 + l * 1024);

    // ---- feedforward
    ln_kernel<<<MROWS, 256, 0, stream>>>(xout, ln2w + l * 1024,
                                         ln2b + l * 1024, h_bf);
    gemm_bt<128, 128, 2, 2, 1><<<dim3(64, 16, 1), 256, 0, stream>>>(
        h_bf, 0, 0, 1024, wff1T, 0, 0, 1024, u_bf, 0, 0, 8192, 1024, 1.f,
        bff1 + l * 8192, nullptr);
    geglu_kernel<<<8192, 256, 0, stream>>>(u_bf, ff_bf);
    // x += (ff @ w_ff2 + b_ff2) * ls2
    gemm_bt<128, 128, 2, 2, 2><<<dim3(8, 16, 1), 256, 0, stream>>>(
        ff_bf, 0, 0, 4096, wff2T, 0, 0, 4096, xout, 0, 0, 1024, 4096, 1.f,
        bff2 + l * 1024, ls2 + l * 1024);
  }
}

// Round 2
// 1225.925 us; speedup vs baseline: 1.2152x; 1.2152x over previous
//
#include <hip/hip_runtime.h>
#include <cstdint>
#include <cstddef>

// ---------------------------------------------------------------- types
typedef __bf16 bf16_t;
typedef __bf16 bf16x8 __attribute__((ext_vector_type(8)));
typedef __bf16 bf16x4 __attribute__((ext_vector_type(4)));
typedef float  f32x4  __attribute__((ext_vector_type(4)));

#define DEV __device__ __forceinline__

static constexpr int   BATCH = 2;
static constexpr int   NTOK  = 1024;
static constexpr int   DIM   = 1024;
static constexpr int   MROWS = BATCH * NTOK;      // 2048 token rows
static constexpr float SCALE = 0.125f;            // 64^-0.5

// ------------------------------------------------------- global->LDS DMA
DEV void load_lds16(const bf16_t* g, bf16_t* s) {
  __builtin_amdgcn_global_load_lds(
      (const __attribute__((address_space(1))) void*)g,
      (__attribute__((address_space(3))) void*)s, 16, 0, 0);
}

// ------------------------------------------------------------ reductions
DEV float wave_sum(float v) {
#pragma unroll
  for (int m = 1; m < 64; m <<= 1) v += __shfl_xor(v, m, 64);
  return v;
}
DEV float block_sum(float v, float* sb) {
  v = wave_sum(v);
  __syncthreads();
  if ((threadIdx.x & 63) == 0) sb[threadIdx.x >> 6] = v;
  __syncthreads();
  return sb[0] + sb[1] + sb[2] + sb[3];
}

// ------------------------------------------------------------------ GEMM
// C[M,N] = A[M,K] @ B[K,N], with B given transposed: BT[N][K] (row-major).
// Fragment layout (verified in-round):
//   A frag:  A[m = lane&15][k = (lane>>4)*8 + j]   -> 8 contiguous bf16
//   B frag:  BT[n = lane&15][k = (lane>>4)*8 + j]  -> 8 contiguous bf16
//   C/D:     col = lane&15, row = (lane>>4)*4 + reg
// MODE 0: C(bf16) = alpha * acc
// MODE 1: C(bf16) = acc + bias[col]
// MODE 2: C(f32) += (acc + bias[col]) * ls[col]   (residual update in place)
template <int BM, int BN, int WR, int WC, int MODE>
__global__ __launch_bounds__(256) void gemm_bt(
    const bf16_t* __restrict__ A, long sA0, long sA1, int lda,
    const bf16_t* __restrict__ B, long sB0, long sB1, int ldb,
    void* __restrict__ Cv, long sC0, long sC1, int ldc,
    int K, float alpha, const float* __restrict__ bias,
    const float* __restrict__ ls) {
  constexpr int TM = BM / WR / 16;
  constexpr int TN = BN / WC / 16;
  __shared__ __attribute__((aligned(16))) bf16_t As[BM * 32];
  __shared__ __attribute__((aligned(16))) bf16_t Bs[BN * 32];

  const int tid  = threadIdx.x;
  const int lane = tid & 63, wave = tid >> 6;
  const int z  = blockIdx.z;
  const int zh = z >> 4, zl = z & 15;
  A += (size_t)zh * sA0 + (size_t)zl * sA1;
  B += (size_t)zh * sB0 + (size_t)zl * sB1;

  const int m0 = blockIdx.y * BM, n0 = blockIdx.x * BN;
  const int wm = (wave / WC) * (BM / WR);
  const int wn = (wave % WC) * (BN / WC);
  const int fm = lane & 15, quad = lane >> 4;

  f32x4 acc[TM][TN] = {};

  for (int k0 = 0; k0 < K; k0 += 32) {
#pragma unroll
    for (int c = tid; c < BM * 4; c += 256) {
      const int row = c >> 2, kc = (c & 3) << 3;
      load_lds16(A + (size_t)(m0 + row) * lda + k0 + kc, &As[c * 8]);
    }
#pragma unroll
    for (int c = tid; c < BN * 4; c += 256) {
      const int row = c >> 2, kc = (c & 3) << 3;
      load_lds16(B + (size_t)(n0 + row) * ldb + k0 + kc, &Bs[c * 8]);
    }
    __syncthreads();

    bf16x8 af[TM], bfr[TN];
#pragma unroll
    for (int i = 0; i < TM; ++i)
      af[i] = *(const bf16x8*)&As[(wm + i * 16 + fm) * 32 + quad * 8];
#pragma unroll
    for (int j = 0; j < TN; ++j)
      bfr[j] = *(const bf16x8*)&Bs[(wn + j * 16 + fm) * 32 + quad * 8];
#pragma unroll
    for (int i = 0; i < TM; ++i)
#pragma unroll
      for (int j = 0; j < TN; ++j)
        acc[i][j] = __builtin_amdgcn_mfma_f32_16x16x32_bf16(af[i], bfr[j],
                                                            acc[i][j], 0, 0, 0);
    __syncthreads();
  }

  const size_t coff = (size_t)zh * sC0 + (size_t)zl * sC1;
#pragma unroll
  for (int i = 0; i < TM; ++i) {
#pragma unroll
    for (int j = 0; j < TN; ++j) {
      const int col  = n0 + wn + j * 16 + fm;
      const int rowb = m0 + wm + i * 16 + quad * 4;
#pragma unroll
      for (int r = 0; r < 4; ++r) {
        const float  v   = acc[i][j][r];
        const size_t idx = coff + (size_t)(rowb + r) * ldc + col;
        if constexpr (MODE == 0) {
          ((bf16_t*)Cv)[idx] = (bf16_t)(v * alpha);
        } else if constexpr (MODE == 1) {
          ((bf16_t*)Cv)[idx] = (bf16_t)(v + bias[col]);
        } else {
          float* C = (float*)Cv;
          C[idx]   = C[idx] + (v + bias[col]) * ls[col];
        }
      }
    }
  }
}

// --------------------------------------------------------- flash attention
// One block per (64-row Q tile, z = b*16+h). 4 waves, each owning 16 Q rows.
// KV tiles of 128 tokens. S never hits HBM.
// LDS layouts are [k-chunk][row][32] so fragment reads are 64B-stride
// ds_read_b128 (m97 pattern), matching global_load_lds lane-contiguity.
__global__ __launch_bounds__(256) void flash_attn(
    const bf16_t* __restrict__ qkv,   // [2][1024][3072]
    const bf16_t* __restrict__ vT,    // [32][64][1024]
    bf16_t* __restrict__ o) {         // [2][1024][1024] col = h*64+d
  constexpr int NT = 128;
  __shared__ __attribute__((aligned(16))) bf16_t Qs[2 * 64 * 32];   // 8 KB
  __shared__ __attribute__((aligned(16))) bf16_t Ks[2 * NT * 32];   // 16 KB
  __shared__ __attribute__((aligned(16))) bf16_t Vs[4 * 64 * 32];   // 16 KB
  __shared__ __attribute__((aligned(16))) bf16_t Ps[4][4 * 16 * 32];// 16 KB

  const int tid = threadIdx.x, lane = tid & 63, wave = tid >> 6;
  const int fm = lane & 15, quad = lane >> 4;
  const int z = blockIdx.y, b = z >> 4, h = z & 15;
  const int q0 = blockIdx.x * 64;
  const bf16_t* qb  = qkv + (size_t)b * 1024 * 3072 + h * 64;
  const bf16_t* kb  = qb + 1024;
  const bf16_t* vtb = vT + (size_t)z * 64 * 1024;

  // stage Q tile: layout [kk(2)][row(64)][32]
  for (int c = tid; c < 512; c += 256) {
    const int kk = c >> 8, rr = (c >> 2) & 63, ii = c & 3;
    load_lds16(qb + (size_t)(q0 + rr) * 3072 + kk * 32 + ii * 8, &Qs[c * 8]);
  }
  __syncthreads();
  bf16x8 qf[2];
  qf[0] = *(const bf16x8*)&Qs[(wave * 16 + fm) * 32 + quad * 8];
  qf[1] = *(const bf16x8*)&Qs[64 * 32 + (wave * 16 + fm) * 32 + quad * 8];

  float mr[4], lr[4];
  f32x4 oacc[4];
#pragma unroll
  for (int r = 0; r < 4; ++r) { mr[r] = -1e30f; lr[r] = 0.f; }
#pragma unroll
  for (int t = 0; t < 4; ++t) oacc[t] = (f32x4){0.f, 0.f, 0.f, 0.f};

  for (int kv0 = 0; kv0 < 1024; kv0 += NT) {
    __syncthreads();  // all waves done reading previous K/V tiles
    // K tile [kk(2)][tok(128)][32]
    for (int c = tid; c < NT * 8; c += 256) {
      const int kk = c >> 9, rr = (c >> 2) & 127, ii = c & 3;
      load_lds16(kb + (size_t)(kv0 + rr) * 3072 + kk * 32 + ii * 8, &Ks[c * 8]);
    }
    // V^T tile [tc(4)][d(64)][32]
    for (int c = tid; c < 1024; c += 256) {
      const int tc = c >> 8, rr = (c >> 2) & 63, ii = c & 3;
      load_lds16(vtb + (size_t)rr * 1024 + kv0 + tc * 32 + ii * 8, &Vs[c * 8]);
    }
    __syncthreads();

    // S = Q @ K^T  (8 column tiles of 16)
    f32x4 sc[8];
#pragma unroll
    for (int nt = 0; nt < 8; ++nt) {
      sc[nt] = (f32x4){0.f, 0.f, 0.f, 0.f};
#pragma unroll
      for (int kk = 0; kk < 2; ++kk) {
        const bf16x8 kf =
            *(const bf16x8*)&Ks[kk * NT * 32 + (nt * 16 + fm) * 32 + quad * 8];
        sc[nt] = __builtin_amdgcn_mfma_f32_16x16x32_bf16(qf[kk], kf, sc[nt],
                                                         0, 0, 0);
      }
    }
    // online softmax over this tile (rows = quad*4+r, cols across 16 lanes)
    float tmax[4] = {-1e30f, -1e30f, -1e30f, -1e30f};
#pragma unroll
    for (int nt = 0; nt < 8; ++nt)
#pragma unroll
      for (int r = 0; r < 4; ++r) {
        sc[nt][r] *= SCALE;
        tmax[r] = fmaxf(tmax[r], sc[nt][r]);
      }
#pragma unroll
    for (int m = 1; m < 16; m <<= 1)
#pragma unroll
      for (int r = 0; r < 4; ++r)
        tmax[r] = fmaxf(tmax[r], __shfl_xor(tmax[r], m, 64));
    float alpha[4], mn[4], ps[4];
#pragma unroll
    for (int r = 0; r < 4; ++r) {
      mn[r]    = fmaxf(mr[r], tmax[r]);
      alpha[r] = __expf(mr[r] - mn[r]);
      mr[r]    = mn[r];
      ps[r]    = 0.f;
    }
    // P = exp(S - m); write to per-wave LDS in [kk(4)][m(16)][32] layout
#pragma unroll
    for (int nt = 0; nt < 8; ++nt) {
      const int tcol = nt * 16 + fm, kk = tcol >> 5, tw = tcol & 31;
#pragma unroll
      for (int r = 0; r < 4; ++r) {
        const float p = __expf(sc[nt][r] - mn[r]);
        ps[r] += p;
        Ps[wave][kk * 512 + (quad * 4 + r) * 32 + tw] = (bf16_t)p;
      }
    }
#pragma unroll
    for (int m = 1; m < 16; m <<= 1)
#pragma unroll
      for (int r = 0; r < 4; ++r) ps[r] += __shfl_xor(ps[r], m, 64);
#pragma unroll
    for (int r = 0; r < 4; ++r) lr[r] = lr[r] * alpha[r] + ps[r];
#pragma unroll
    for (int t = 0; t < 4; ++t)
#pragma unroll
      for (int r = 0; r < 4; ++r) oacc[t][r] *= alpha[r];
    // drain this wave's LDS writes of P before reading fragments
    __builtin_amdgcn_s_waitcnt(0xC07F);  // lgkmcnt(0), vm/exp unconstrained
    // O += P @ V
#pragma unroll
    for (int kk = 0; kk < 4; ++kk) {
      const bf16x8 af =
          *(const bf16x8*)&Ps[wave][kk * 512 + fm * 32 + quad * 8];
#pragma unroll
      for (int t = 0; t < 4; ++t) {
        const bf16x8 vf =
            *(const bf16x8*)&Vs[kk * 64 * 32 + (t * 16 + fm) * 32 + quad * 8];
        oacc[t] = __builtin_amdgcn_mfma_f32_16x16x32_bf16(af, vf, oacc[t],
                                                          0, 0, 0);
      }
    }
  }

  // epilogue: normalize and store (C layout)
  const size_t orow0 = (size_t)b * 1024 + q0 + wave * 16 + quad * 4;
#pragma unroll
  for (int t = 0; t < 4; ++t) {
    const int col = h * 64 + t * 16 + fm;
#pragma unroll
    for (int r = 0; r < 4; ++r)
      o[(orow0 + r) * 1024 + col] = (bf16_t)(oacc[t][r] / lr[r]);
  }
}

// ------------------------------------------------- weight transpose+cast
// W[K][N] fp32 -> WT[N][K] bf16.  grid(N/32, K/32), 256 thr.
__global__ __launch_bounds__(256) void transpose_w(const float* __restrict__ W,
                                                   bf16_t* __restrict__ WT,
                                                   int K, int N) {
  __shared__ float t[32][33];
  const int n0 = blockIdx.x * 32, k0 = blockIdx.y * 32;
  const int tx = threadIdx.x & 31, ty = threadIdx.x >> 5;
#pragma unroll
  for (int s = 0; s < 4; ++s)
    t[ty + 8 * s][tx] = W[(size_t)(k0 + ty + 8 * s) * N + n0 + tx];
  __syncthreads();
#pragma unroll
  for (int s = 0; s < 4; ++s)
    WT[(size_t)(n0 + ty + 8 * s) * K + k0 + tx] = (bf16_t)t[tx][ty + 8 * s];
}

// ----------------------------------------------------- V transpose (bf16)
// qkv[b*1024+tok][2048 + h*64 + d] -> vT[z=b*16+h][d][tok]
__global__ __launch_bounds__(256) void transpose_v(const bf16_t* __restrict__ qkv,
                                                   bf16_t* __restrict__ vT) {
  __shared__ bf16_t t[32][33];
  const int z = blockIdx.z, b = z >> 4, h = z & 15;
  const int d0 = blockIdx.y * 32, n0 = blockIdx.x * 32;
  const int tx = threadIdx.x & 31, ty = threadIdx.x >> 5;
  const bf16_t* src = qkv + (size_t)b * NTOK * 3072 + 2048 + h * 64;
#pragma unroll
  for (int s = 0; s < 4; ++s)
    t[ty + 8 * s][tx] = src[(size_t)(n0 + ty + 8 * s) * 3072 + d0 + tx];
  __syncthreads();
  bf16_t* dst = vT + (size_t)z * 64 * NTOK;
#pragma unroll
  for (int s = 0; s < 4; ++s)
    dst[(size_t)(d0 + ty + 8 * s) * NTOK + n0 + tx] = t[tx][ty + 8 * s];
}

// -------------------------------------------------------------- layernorm
__global__ __launch_bounds__(256) void ln_kernel(const float* __restrict__ x,
                                                 const float* __restrict__ w,
                                                 const float* __restrict__ b,
                                                 bf16_t* __restrict__ out) {
  __shared__ float sb[4];
  const int row = blockIdx.x, tid = threadIdx.x;
  const float4 v = ((const float4*)(x + (size_t)row * DIM))[tid];
  float s = v.x + v.y + v.z + v.w;
  s = block_sum(s, sb);
  const float mu = s * (1.f / DIM);
  const float dx = v.x - mu, dy = v.y - mu, dz = v.z - mu, dw = v.w - mu;
  float q = dx * dx + dy * dy + dz * dz + dw * dw;
  q = block_sum(q, sb);
  const float rstd = rsqrtf(q * (1.f / DIM) + 1e-5f);
  const float4 wv = ((const float4*)w)[tid];
  const float4 bv = ((const float4*)b)[tid];
  bf16x4 o;
  o[0] = (bf16_t)(dx * rstd * wv.x + bv.x);
  o[1] = (bf16_t)(dy * rstd * wv.y + bv.y);
  o[2] = (bf16_t)(dz * rstd * wv.z + bv.z);
  o[3] = (bf16_t)(dw * rstd * wv.w + bv.w);
  ((bf16x4*)(out + (size_t)row * DIM))[tid] = o;
}

// ------------------------------------------------------------------ geglu
__global__ __launch_bounds__(256) void geglu_kernel(const bf16_t* __restrict__ u,
                                                    bf16_t* __restrict__ ff) {
  const int g   = blockIdx.x * 256 + threadIdx.x;
  const int row = g >> 10, cg = (g & 1023) * 4;
  const bf16x4 av = *(const bf16x4*)(u + (size_t)row * 8192 + cg);
  const bf16x4 gv = *(const bf16x4*)(u + (size_t)row * 8192 + 4096 + cg);
  bf16x4 o;
#pragma unroll
  for (int c = 0; c < 4; ++c) {
    const float gx = (float)gv[c];
    const float ge = 0.5f * gx * (1.f + erff(gx * 0.70710678118654752f));
    o[c] = (bf16_t)((float)av[c] * ge);
  }
  *(bf16x4*)(ff + (size_t)row * 4096 + cg) = o;
}

// ------------------------------------------------------------------ launch
extern "C" void kernel_launch(void* const* d_in, const int* in_sizes, int n_in,
                              void* d_out, int out_size, void* d_ws,
                              size_t ws_size, hipStream_t stream) {
  const float* x_in = (const float*)d_in[0];
  const float* ln1w = (const float*)d_in[1];
  const float* ln1b = (const float*)d_in[2];
  const float* wqkv = (const float*)d_in[3];
  const float* wout = (const float*)d_in[4];
  const float* bout = (const float*)d_in[5];
  const float* ls1  = (const float*)d_in[6];
  const float* ln2w = (const float*)d_in[7];
  const float* ln2b = (const float*)d_in[8];
  const float* wff1 = (const float*)d_in[9];
  const float* bff1 = (const float*)d_in[10];
  const float* wff2 = (const float*)d_in[11];
  const float* bff2 = (const float*)d_in[12];
  const float* ls2  = (const float*)d_in[13];
  float*       xout = (float*)d_out;

  // -------- workspace carve-up (~109 MB)
  char*   ws     = (char*)d_ws;
  bf16_t* wqkvT  = (bf16_t*)ws; ws += (size_t)3072 * 1024 * 2;   // 6.3 MB
  bf16_t* woutT  = (bf16_t*)ws; ws += (size_t)1024 * 1024 * 2;   // 2.1 MB
  bf16_t* wff1T  = (bf16_t*)ws; ws += (size_t)8192 * 1024 * 2;   // 16.8 MB
  bf16_t* wff2T  = (bf16_t*)ws; ws += (size_t)1024 * 4096 * 2;   // 8.4 MB
  bf16_t* h_bf   = (bf16_t*)ws; ws += (size_t)MROWS * 1024 * 2;  // 4.2 MB
  bf16_t* qkv_bf = (bf16_t*)ws; ws += (size_t)MROWS * 3072 * 2;  // 12.6 MB
  bf16_t* o_bf   = (bf16_t*)ws; ws += (size_t)MROWS * 1024 * 2;  // 4.2 MB
  bf16_t* vT     = (bf16_t*)ws; ws += (size_t)32 * 64 * 1024 * 2;// 4.2 MB
  bf16_t* u_bf   = (bf16_t*)ws; ws += (size_t)MROWS * 8192 * 2;  // 33.6 MB
  bf16_t* ff_bf  = (bf16_t*)ws; ws += (size_t)MROWS * 4096 * 2;  // 16.8 MB
  if (ws_size < (size_t)(ws - (char*)d_ws)) return;  // visible fail

  hipMemcpyAsync(xout, x_in, (size_t)MROWS * DIM * 4,
                 hipMemcpyDeviceToDevice, stream);

  for (int l = 0; l < 4; ++l) {
    // ---- per-layer weight transpose+cast
    transpose_w<<<dim3(3072 / 32, 1024 / 32), 256, 0, stream>>>(
        wqkv + (size_t)l * 1024 * 3072, wqkvT, 1024, 3072);
    transpose_w<<<dim3(1024 / 32, 1024 / 32), 256, 0, stream>>>(
        wout + (size_t)l * 1024 * 1024, woutT, 1024, 1024);
    transpose_w<<<dim3(8192 / 32, 1024 / 32), 256, 0, stream>>>(
        wff1 + (size_t)l * 1024 * 8192, wff1T, 1024, 8192);
    transpose_w<<<dim3(1024 / 32, 4096 / 32), 256, 0, stream>>>(
        wff2 + (size_t)l * 4096 * 1024, wff2T, 4096, 1024);

    // ---- attention
    ln_kernel<<<MROWS, 256, 0, stream>>>(xout, ln1w + l * 1024,
                                         ln1b + l * 1024, h_bf);
    gemm_bt<128, 128, 2, 2, 0><<<dim3(24, 16, 1), 256, 0, stream>>>(
        h_bf, 0, 0, 1024, wqkvT, 0, 0, 1024, qkv_bf, 0, 0, 3072, 1024, 1.f,
        nullptr, nullptr);
    transpose_v<<<dim3(32, 2, 32), 256, 0, stream>>>(qkv_bf, vT);
    flash_attn<<<dim3(16, 32), 256, 0, stream>>>(qkv_bf, vT, o_bf);
    // x += (o @ w_out + b_out) * ls1   (256 blocks: 64x128 tiles)
    gemm_bt<64, 128, 1, 4, 2><<<dim3(8, 32, 1), 256, 0, stream>>>(
        o_bf, 0, 0, 1024, woutT, 0, 0, 1024, xout, 0, 0, 1024, 1024, 1.f,
        bout + l * 1024, ls1 + l * 1024);

    // ---- feedforward
    ln_kernel<<<MROWS, 256, 0, stream>>>(xout, ln2w + l * 1024,
                                         ln2b + l * 1024, h_bf);
    gemm_bt<128, 128, 2, 2, 1><<<dim3(64, 16, 1), 256, 0, stream>>>(
        h_bf, 0, 0, 1024, wff1T, 0, 0, 1024, u_bf, 0, 0, 8192, 1024, 1.f,
        bff1 + l * 8192, nullptr);
    geglu_kernel<<<8192, 256, 0, stream>>>(u_bf, ff_bf);
    // x += (ff @ w_ff2 + b_ff2) * ls2  (256 blocks: 64x128 tiles)
    gemm_bt<64, 128, 1, 4, 2><<<dim3(8, 32, 1), 256, 0, stream>>>(
        ff_bf, 0, 0, 4096, wff2T, 0, 0, 4096, xout, 0, 0, 1024, 4096, 1.f,
        bff2 + l * 1024, ls2 + l * 1024);
  }
}